// Round 2
// baseline (1182.514 us; speedup 1.0000x reference)
//
#include <hip/hip_runtime.h>
#include <hip/hip_bf16.h>
#include <stdint.h>

#define IN_F   4096
#define OUT_F  11008
#define M_TOT  8192
#define ZCOLS  (OUT_F / 8)      // 1376
#define KK_ROWS (IN_F / 8)      // 512

#define BM 256
#define BN 256
#define BK 64
#define NT (IN_F / BK)          // 64 K-tiles
#define GRID_M (M_TOT / BM)     // 32
#define GRID_N (OUT_F / BN)     // 43
#define NWG (GRID_M * GRID_N)   // 1376 (divisible by 8)
#define CPX (NWG / 8)           // 172

typedef __attribute__((ext_vector_type(8)))  short  bf16x8;
typedef __attribute__((ext_vector_type(8)))  ushort ushort8;
typedef __attribute__((ext_vector_type(16))) float  f32x16;

__device__ __forceinline__ ushort f2bf(float f) {
    __hip_bfloat16 h = __float2bfloat16(f);   // RTNE
    return *reinterpret_cast<ushort*>(&h);
}

// ---------------- Phase 1: x fp32 -> bf16 (8 floats / thread, 16B store) ----
__global__ void convert_x(const float4* __restrict__ x, ushort8* __restrict__ xb) {
    size_t t = (size_t)blockIdx.x * 256 + threadIdx.x;   // 4,194,304 threads
    float4 a = x[2 * t];
    float4 b = x[2 * t + 1];
    ushort8 o;
    o[0] = f2bf(a.x); o[1] = f2bf(a.y); o[2] = f2bf(a.z); o[3] = f2bf(a.w);
    o[4] = f2bf(b.x); o[5] = f2bf(b.y); o[6] = f2bf(b.z); o[7] = f2bf(b.w);
    xb[t] = o;
}

// ---------------- Phase 2: dequant -> Wt [N][K] bf16, LDS tile transpose ----
// Tile: 64 n-cols x 64 kk-rows (512 k). Reads coalesced along n; XOR-swizzled
// LDS transpose buffer; writes coalesced along k (1 KiB contiguous per row).
__global__ __launch_bounds__(256)
void dequant_w(const int* __restrict__ qw, const int* __restrict__ qz,
               const float* __restrict__ sc, ushort* __restrict__ wt) {
    __shared__ ushort tile[64 * 512];          // 64 KiB -> 2 blocks/CU

    const int bid = blockIdx.x;                // 1376 blocks
    const int n0  = (bid % (OUT_F / 64)) * 64;
    const int kk0 = (bid / (OUT_F / 64)) * 64;
    const int tid = threadIdx.x;
    const int nl  = tid & 63;
    const int kr  = tid >> 6;                  // 0..3

    const int ng  = n0 + nl;
    const int zsh = (ng & 7) * 4;
    const int zc  = ng >> 3;

#pragma unroll
    for (int p = 0; p < 16; ++p) {
        const int kk  = p * 4 + kr;            // 0..63
        const int gkk = kk0 + kk;
        const int g   = gkk >> 4;
        const int w   = qw[gkk * OUT_F + ng];                    // coalesced (n-contig)
        const int z   = (qz[g * ZCOLS + zc] >> zsh) & 15;
        const float s = sc[g * OUT_F + ng];                      // coalesced
        ushort8 r;
#pragma unroll
        for (int i = 0; i < 8; ++i) {
            int q = (w >> (4 * i)) & 15;
            r[i] = f2bf((float)(q - z) * s);
        }
        // row nl, 16B chunk kk, XOR-swizzled within the 1 KiB row
        *(ushort8*)&tile[nl * 512 + ((kk * 8) ^ (nl << 3 & 511))] = r;
    }
    __syncthreads();

    const int c   = tid & 63;                  // k-chunk within row
    const int nr4 = tid >> 6;
#pragma unroll
    for (int p = 0; p < 16; ++p) {
        const int nr = p * 4 + nr4;
        ushort8 v = *(const ushort8*)&tile[nr * 512 + ((c * 8) ^ (nr << 3 & 511))];
        *(ushort8*)&wt[(size_t)(n0 + nr) * IN_F + kk0 * 8 + c * 8] = v;   // coalesced
    }
}

// ---------------- Phase 3: 256x256 8-phase GEMM (32x32x16), C = A@Bt^T + b --
// A  [M, K] bf16 row-major; Bt [N, K] bf16 row-major (W^T); C [M, N] fp32
// LDS: smem[8][8192] ushorts = 128 KiB; region = buf*4 + mat*2 + half.
// Element (r,c) of a region lives at byte (r*128 + (c*2 ^ ((r&7)<<4)));
// global_load_lds writes LINEAR dest, source address pre-inverse-swizzled.
__global__ __launch_bounds__(512, 2)
void gemm_bf16(const ushort* __restrict__ A, const ushort* __restrict__ Bt,
               const float* __restrict__ bias, float* __restrict__ C) {
    __shared__ ushort smem[8][8192];   // 128 KiB

    const int tid  = threadIdx.x;
    const int wave = tid >> 6;
    const int lane = tid & 63;

    // T1: XCD-aware bijective swizzle (nwg % 8 == 0)
    const int bid = blockIdx.x;
    const int swz = (bid & 7) * CPX + (bid >> 3);
    const int bm0 = (swz / GRID_N) * BM;
    const int bn0 = (swz % GRID_N) * BN;

    const int wm = wave >> 2;     // 0..1  (M half of C-tile)
    const int wn = wave & 3;      // 0..3  (N quarter)
    const int la = lane & 31;     // 32x32 row/col within tile
    const int lh = lane >> 5;     // k-half selector

    // ---- staging constants (inverse-swizzled global source) ----
    const int sr   = lane >> 3;                    // 0..7 (row within 8-row group)
    const int scol = 8 * ((lane & 7) ^ sr);        // swizzled col, ushort units

    const ushort* aSrc[2][2];   // [mh][j]
    const ushort* bSrc[2][2];   // [nh][j]
#pragma unroll
    for (int j = 0; j < 2; ++j) {
        const int r = wave * 16 + j * 8 + sr;      // region-linear row 0..127
#pragma unroll
        for (int h = 0; h < 2; ++h) {
            aSrc[h][j] = A  + (size_t)(bm0 + ((r >> 6) << 7) + h * 64 + (r & 63)) * IN_F + scol;
            bSrc[h][j] = Bt + (size_t)(bn0 + ((r >> 5) << 6) + h * 32 + (r & 31)) * IN_F + scol;
        }
    }

    // ---- ds_read column offsets (swizzled), ushort units ----
    // frag (ks, lh): logical col = ks*16 + lh*8; row&7 == la&7 for all reads
    const int sw8 = (la & 7) << 3;
    int cof[4];
#pragma unroll
    for (int ks = 0; ks < 4; ++ks)
        cof[ks] = (ks * 16 + lh * 8) ^ sw8;

    f32x16 acc[4][2] = {};      // [mtile(32 rows)][ntile(32 cols)]
    bf16x8 af[2][4];            // [mtile-in-half][kstep]
    bf16x8 bfv[4];              // [kstep], current n-half

#define STAGE_A(buf, mh, kt) do {                                                        \
    _Pragma("unroll")                                                                    \
    for (int j_ = 0; j_ < 2; ++j_)                                                       \
        __builtin_amdgcn_global_load_lds(                                                \
            (const __attribute__((address_space(1))) void*)(aSrc[mh][j_] + (size_t)(kt) * BK), \
            (__attribute__((address_space(3))) void*)(&smem[(buf) * 4 + (mh)][(wave * 2 + j_) * 512]), \
            16, 0, 0);                                                                   \
} while (0)

#define STAGE_B(buf, nh, kt) do {                                                        \
    _Pragma("unroll")                                                                    \
    for (int j_ = 0; j_ < 2; ++j_)                                                       \
        __builtin_amdgcn_global_load_lds(                                                \
            (const __attribute__((address_space(1))) void*)(bSrc[nh][j_] + (size_t)(kt) * BK), \
            (__attribute__((address_space(3))) void*)(&smem[(buf) * 4 + 2 + (nh)][(wave * 2 + j_) * 512]), \
            16, 0, 0);                                                                   \
} while (0)

#define LDA(buf, mh) do {                                                                \
    const ushort* ab_ = &smem[(buf) * 4 + (mh)][(wm * 64 + la) * 64];                    \
    _Pragma("unroll")                                                                    \
    for (int i_ = 0; i_ < 2; ++i_)                                                       \
        _Pragma("unroll")                                                                \
        for (int ks_ = 0; ks_ < 4; ++ks_)                                                \
            af[i_][ks_] = *(const bf16x8*)(ab_ + i_ * 2048 + cof[ks_]);                  \
} while (0)

#define LDB(buf, nh) do {                                                                \
    const ushort* bb_ = &smem[(buf) * 4 + 2 + (nh)][(wn * 32 + la) * 64];                \
    _Pragma("unroll")                                                                    \
    for (int ks_ = 0; ks_ < 4; ++ks_)                                                    \
        bfv[ks_] = *(const bf16x8*)(bb_ + cof[ks_]);                                     \
} while (0)

#define MFMA_Q(mh, nh) do {                                                              \
    __builtin_amdgcn_s_setprio(1);                                                       \
    _Pragma("unroll")                                                                    \
    for (int i_ = 0; i_ < 2; ++i_)                                                       \
        _Pragma("unroll")                                                                \
        for (int ks_ = 0; ks_ < 4; ++ks_)                                                \
            acc[(mh) * 2 + i_][nh] = __builtin_amdgcn_mfma_f32_32x32x16_bf16(            \
                af[i_][ks_], bfv[ks_], acc[(mh) * 2 + i_][nh], 0, 0, 0);                 \
    __builtin_amdgcn_s_setprio(0);                                                       \
} while (0)

#define BAR()   asm volatile("s_barrier" ::: "memory")
#define LGKM0() asm volatile("s_waitcnt lgkmcnt(0)" ::: "memory")
#define VM(n)   asm volatile("s_waitcnt vmcnt(" #n ")" ::: "memory")

    // ---- prologue: tile0 {A0,B1,A1,B0} + tile1 {A0,B1,A1}; 14 loads, keep 6 in flight
    STAGE_A(0, 0, 0);
    STAGE_B(0, 1, 0);
    STAGE_A(0, 1, 0);
    STAGE_B(0, 0, 0);
    STAGE_A(1, 0, 1);
    STAGE_B(1, 1, 1);
    STAGE_A(1, 1, 1);
    VM(6);
    BAR();

#pragma unroll 1
    for (int it = 0; it < NT / 2; ++it) {
        const int t1 = 2 * it + 1;
        int s2 = 2 * it + 2; if (s2 > NT - 1) s2 = NT - 1;   // clamp: uniform inst count
        int s3 = 2 * it + 3; if (s3 > NT - 1) s3 = NT - 1;

        // ph1: buf0 (mh0,nh0); stage B0(t1)->buf1
        LDA(0, 0); LDB(0, 0);
        STAGE_B(1, 0, t1);
        BAR(); LGKM0();
        MFMA_Q(0, 0);
        BAR();

        // ph2: buf0 (mh0,nh1), reuse A frags; stage A0(s2)->buf0
        LDB(0, 1);
        STAGE_A(0, 0, s2);
        BAR(); LGKM0();
        MFMA_Q(0, 1);
        BAR();

        // ph3: buf0 (mh1,nh1), reuse B frags; stage B1(s2)->buf0
        LDA(0, 1);
        STAGE_B(0, 1, s2);
        BAR(); LGKM0();
        MFMA_Q(1, 1);
        BAR();

        // ph4: buf0 (mh1,nh0), reuse A frags; stage A1(s2)->buf0; counted vmcnt
        LDB(0, 0);
        STAGE_A(0, 1, s2);
        BAR(); LGKM0();
        MFMA_Q(1, 0);
        VM(6);
        BAR();

        // ph5: buf1 (mh0,nh0); stage B0(s2)->buf0
        LDA(1, 0); LDB(1, 0);
        STAGE_B(0, 0, s2);
        BAR(); LGKM0();
        MFMA_Q(0, 0);
        BAR();

        // ph6: buf1 (mh0,nh1); stage A0(s3)->buf1
        LDB(1, 1);
        STAGE_A(1, 0, s3);
        BAR(); LGKM0();
        MFMA_Q(0, 1);
        BAR();

        // ph7: buf1 (mh1,nh1); stage B1(s3)->buf1
        LDA(1, 1);
        STAGE_B(1, 1, s3);
        BAR(); LGKM0();
        MFMA_Q(1, 1);
        BAR();

        // ph8: buf1 (mh1,nh0); stage A1(s3)->buf1; counted vmcnt
        LDB(1, 0);
        STAGE_A(1, 1, s3);
        BAR(); LGKM0();
        MFMA_Q(1, 0);
        VM(6);
        BAR();
    }

    VM(0);   // drain outstanding prefetches before epilogue

    // epilogue: 32x32 C/D layout: col = la, row = (reg&3) + 8*(reg>>2) + 4*lh
    // C row = bm0 + wm*128 + i*32 + lh*4 + rg*8 + r; col = bn0 + wn*64 + j*32 + la
#pragma unroll
    for (int j = 0; j < 2; ++j) {
        const int n = bn0 + wn * 64 + j * 32 + la;
        const float bv = bias[n];
#pragma unroll
        for (int i = 0; i < 4; ++i) {
            const int rowb = bm0 + wm * 128 + i * 32 + lh * 4;
#pragma unroll
            for (int rg = 0; rg < 4; ++rg) {
                float* out = C + (size_t)(rowb + rg * 8) * OUT_F + n;
#pragma unroll
                for (int r = 0; r < 4; ++r)
                    out[(size_t)r * OUT_F] = acc[i][j][rg * 4 + r] + bv;
            }
        }
    }

#undef STAGE_A
#undef STAGE_B
#undef LDA
#undef LDB
#undef MFMA_Q
#undef BAR
#undef LGKM0
#undef VM
}

extern "C" void kernel_launch(void* const* d_in, const int* in_sizes, int n_in,
                              void* d_out, int out_size, void* d_ws, size_t ws_size,
                              hipStream_t stream) {
    const float* x       = (const float*)d_in[0];  // [4,2048,4096]
    const float* scales  = (const float*)d_in[1];  // [32,11008]
    const float* bias    = (const float*)d_in[2];  // [11008]
    const int*   qweight = (const int*)d_in[3];    // [512,11008]
    const int*   qzeros  = (const int*)d_in[4];    // [32,1376]
    float* out = (float*)d_out;                    // [8192,11008]

    // workspace: xb (67,108,864 B) | wt (90,177,536 B)
    ushort* xb = (ushort*)d_ws;
    ushort* wt = (ushort*)((char*)d_ws + (size_t)M_TOT * IN_F * 2);

    convert_x<<<(M_TOT * IN_F / 8) / 256, 256, 0, stream>>>((const float4*)x, (ushort8*)xb);
    dequant_w<<<(OUT_F / 64) * (KK_ROWS / 64), 256, 0, stream>>>(qweight, qzeros, scales, wt);
    gemm_bf16<<<NWG, 512, 0, stream>>>(xb, wt, bias, out);
}

// Round 3
// 1074.340 us; speedup vs baseline: 1.1007x; 1.1007x over previous
//
#include <hip/hip_runtime.h>
#include <hip/hip_bf16.h>
#include <stdint.h>

#define IN_F   4096
#define OUT_F  11008
#define M_TOT  8192
#define ZCOLS  (OUT_F / 8)      // 1376
#define KK_ROWS (IN_F / 8)      // 512

#define BM 256
#define BN 256
#define BK 64
#define NT (IN_F / BK)          // 64 K-tiles
#define GRID_M (M_TOT / BM)     // 32
#define GRID_N (OUT_F / BN)     // 43
#define NWG (GRID_M * GRID_N)   // 1376 (divisible by 8)
#define CPX (NWG / 8)           // 172

typedef __attribute__((ext_vector_type(8))) short  bf16x8;
typedef __attribute__((ext_vector_type(8))) ushort ushort8;
typedef __attribute__((ext_vector_type(4))) float  f32x4;

__device__ __forceinline__ ushort f2bf(float f) {
    __hip_bfloat16 h = __float2bfloat16(f);   // RTNE
    return *reinterpret_cast<ushort*>(&h);
}

// ---------------- Phase 1: x fp32 -> bf16 (8 floats / thread, 16B store) ----
__global__ void convert_x(const float4* __restrict__ x, ushort8* __restrict__ xb) {
    size_t t = (size_t)blockIdx.x * 256 + threadIdx.x;   // 4,194,304 threads
    float4 a = x[2 * t];
    float4 b = x[2 * t + 1];
    ushort8 o;
    o[0] = f2bf(a.x); o[1] = f2bf(a.y); o[2] = f2bf(a.z); o[3] = f2bf(a.w);
    o[4] = f2bf(b.x); o[5] = f2bf(b.y); o[6] = f2bf(b.z); o[7] = f2bf(b.w);
    xb[t] = o;
}

// ---------------- Phase 2: dequant -> Wt [N][K] bf16, LDS tile transpose ----
// Tile: 64 n-cols x 64 kk-rows (512 k). Reads coalesced along n; XOR-swizzled
// LDS transpose buffer; writes coalesced along k (1 KiB contiguous per row).
__global__ __launch_bounds__(256)
void dequant_w(const int* __restrict__ qw, const int* __restrict__ qz,
               const float* __restrict__ sc, ushort* __restrict__ wt) {
    __shared__ ushort tile[64 * 512];          // 64 KiB -> 2 blocks/CU

    const int bid = blockIdx.x;                // 1376 blocks
    const int n0  = (bid % (OUT_F / 64)) * 64;
    const int kk0 = (bid / (OUT_F / 64)) * 64;
    const int tid = threadIdx.x;
    const int nl  = tid & 63;
    const int kr  = tid >> 6;                  // 0..3

    const int ng  = n0 + nl;
    const int zsh = (ng & 7) * 4;
    const int zc  = ng >> 3;

#pragma unroll
    for (int p = 0; p < 16; ++p) {
        const int kk  = p * 4 + kr;            // 0..63
        const int gkk = kk0 + kk;
        const int g   = gkk >> 4;
        const int w   = qw[gkk * OUT_F + ng];                    // coalesced (n-contig)
        const int z   = (qz[g * ZCOLS + zc] >> zsh) & 15;
        const float s = sc[g * OUT_F + ng];                      // coalesced
        ushort8 r;
#pragma unroll
        for (int i = 0; i < 8; ++i) {
            int q = (w >> (4 * i)) & 15;
            r[i] = f2bf((float)(q - z) * s);
        }
        // row nl, 16B chunk kk, XOR-swizzled within the 1 KiB row
        *(ushort8*)&tile[nl * 512 + ((kk * 8) ^ (nl << 3 & 511))] = r;
    }
    __syncthreads();

    const int c   = tid & 63;                  // k-chunk within row
    const int nr4 = tid >> 6;
#pragma unroll
    for (int p = 0; p < 16; ++p) {
        const int nr = p * 4 + nr4;
        ushort8 v = *(const ushort8*)&tile[nr * 512 + ((c * 8) ^ (nr << 3 & 511))];
        *(ushort8*)&wt[(size_t)(n0 + nr) * IN_F + kk0 * 8 + c * 8] = v;   // coalesced
    }
}

// ---------------- Phase 3: 256x256 8-phase GEMM (16x16x32), C = A@Bt^T + b --
// A  [M, K] bf16 row-major; Bt [N, K] bf16 row-major (W^T); C [M, N] fp32
// LDS: smem[8][8192] ushorts = 128 KiB; region = buf*4 + mat*2 + half.
// Element (r,c) of a region lives at byte (r*128 + (c*2 ^ ((r&7)<<4)));
// global_load_lds writes LINEAR dest, source address pre-inverse-swizzled.
// vs round 1: B fragments for BOTH n-halves are register-resident (ball),
// cutting LDS reads 56->48 per 2-K-tiles; stage/vmcnt schedule unchanged.
__global__ __launch_bounds__(512, 2)
void gemm_bf16(const ushort* __restrict__ A, const ushort* __restrict__ Bt,
               const float* __restrict__ bias, float* __restrict__ C) {
    __shared__ ushort smem[8][8192];   // 128 KiB

    const int tid  = threadIdx.x;
    const int wave = tid >> 6;
    const int lane = tid & 63;

    // T1: XCD-aware bijective swizzle (nwg % 8 == 0)
    const int bid = blockIdx.x;
    const int swz = (bid & 7) * CPX + (bid >> 3);
    const int bm0 = (swz / GRID_N) * BM;
    const int bn0 = (swz % GRID_N) * BN;

    const int wm = wave >> 2;     // 0..1  (M half of C-tile)
    const int wn = wave & 3;      // 0..3  (N quarter)
    const int lm = lane & 15;
    const int lq = lane >> 4;

    // ---- staging constants (inverse-swizzled global source) ----
    const int sr   = lane >> 3;                    // 0..7 (row within 8-row group)
    const int scol = 8 * ((lane & 7) ^ sr);        // swizzled col, ushort units

    const ushort* aSrc[2][2];   // [mh][j]
    const ushort* bSrc[2][2];   // [nh][j]
#pragma unroll
    for (int j = 0; j < 2; ++j) {
        const int r = wave * 16 + j * 8 + sr;      // region-linear row 0..127
#pragma unroll
        for (int h = 0; h < 2; ++h) {
            aSrc[h][j] = A  + (size_t)(bm0 + ((r >> 6) << 7) + h * 64 + (r & 63)) * IN_F + scol;
            bSrc[h][j] = Bt + (size_t)(bn0 + ((r >> 5) << 6) + h * 32 + (r & 31)) * IN_F + scol;
        }
    }

    // ---- ds_read column offsets (swizzled), ushort units ----
    const int cswz0 = (lq * 8)      ^ ((lm & 7) << 3);   // ks=0
    const int cswz1 = (32 + lq * 8) ^ ((lm & 7) << 3);   // ks=1

    f32x4  acc[8][4] = {};
    bf16x8 af[4][2];            // A frags, current m-half
    bf16x8 ball[2][2][2];       // B frags, BOTH n-halves: [nh][j][ks]

#define STAGE_A(buf, mh, kt) do {                                                        \
    _Pragma("unroll")                                                                    \
    for (int j_ = 0; j_ < 2; ++j_)                                                       \
        __builtin_amdgcn_global_load_lds(                                                \
            (const __attribute__((address_space(1))) void*)(aSrc[mh][j_] + (size_t)(kt) * BK), \
            (__attribute__((address_space(3))) void*)(&smem[(buf) * 4 + (mh)][(wave * 2 + j_) * 512]), \
            16, 0, 0);                                                                   \
} while (0)

#define STAGE_B(buf, nh, kt) do {                                                        \
    _Pragma("unroll")                                                                    \
    for (int j_ = 0; j_ < 2; ++j_)                                                       \
        __builtin_amdgcn_global_load_lds(                                                \
            (const __attribute__((address_space(1))) void*)(bSrc[nh][j_] + (size_t)(kt) * BK), \
            (__attribute__((address_space(3))) void*)(&smem[(buf) * 4 + 2 + (nh)][(wave * 2 + j_) * 512]), \
            16, 0, 0);                                                                   \
} while (0)

#define LDA(buf, mh) do {                                                                \
    const ushort* ab_ = &smem[(buf) * 4 + (mh)][wm * 4096 + lm * 64];                    \
    _Pragma("unroll")                                                                    \
    for (int i_ = 0; i_ < 4; ++i_) {                                                     \
        af[i_][0] = *(const bf16x8*)(ab_ + i_ * 1024 + cswz0);                           \
        af[i_][1] = *(const bf16x8*)(ab_ + i_ * 1024 + cswz1);                           \
    }                                                                                    \
} while (0)

#define LDB2(buf) do {                                                                   \
    _Pragma("unroll")                                                                    \
    for (int nh_ = 0; nh_ < 2; ++nh_) {                                                  \
        const ushort* bb_ = &smem[(buf) * 4 + 2 + nh_][wn * 2048 + lm * 64];             \
        _Pragma("unroll")                                                                \
        for (int j_ = 0; j_ < 2; ++j_) {                                                 \
            ball[nh_][j_][0] = *(const bf16x8*)(bb_ + j_ * 1024 + cswz0);                \
            ball[nh_][j_][1] = *(const bf16x8*)(bb_ + j_ * 1024 + cswz1);                \
        }                                                                                \
    }                                                                                    \
} while (0)

#define MFMA_Q(mh, nh) do {                                                              \
    __builtin_amdgcn_s_setprio(1);                                                       \
    _Pragma("unroll")                                                                    \
    for (int i_ = 0; i_ < 4; ++i_)                                                       \
        _Pragma("unroll")                                                                \
        for (int j_ = 0; j_ < 2; ++j_)                                                   \
            _Pragma("unroll")                                                            \
            for (int k_ = 0; k_ < 2; ++k_)                                               \
                acc[(mh) * 4 + i_][(nh) * 2 + j_] = __builtin_amdgcn_mfma_f32_16x16x32_bf16( \
                    af[i_][k_], ball[nh][j_][k_], acc[(mh) * 4 + i_][(nh) * 2 + j_], 0, 0, 0); \
    __builtin_amdgcn_s_setprio(0);                                                       \
} while (0)

#define BAR()   asm volatile("s_barrier" ::: "memory")
#define LGKM0() asm volatile("s_waitcnt lgkmcnt(0)" ::: "memory")
#define VM(n)   asm volatile("s_waitcnt vmcnt(" #n ")" ::: "memory")

    // ---- prologue: tile0 {A0,B1,A1,B0} + tile1 {A0,B1,A1}; 14 loads, keep 6 in flight
    STAGE_A(0, 0, 0);
    STAGE_B(0, 1, 0);
    STAGE_A(0, 1, 0);
    STAGE_B(0, 0, 0);
    STAGE_A(1, 0, 1);
    STAGE_B(1, 1, 1);
    STAGE_A(1, 1, 1);
    VM(6);
    BAR();

#pragma unroll 1
    for (int it = 0; it < NT / 2; ++it) {
        const int t1 = 2 * it + 1;
        int s2 = 2 * it + 2; if (s2 > NT - 1) s2 = NT - 1;   // clamp: uniform inst count
        int s3 = 2 * it + 3; if (s3 > NT - 1) s3 = NT - 1;

        // ph1: buf0 (mh0,nh0); read A0 + BOTH B halves; stage B0(t1)->buf1
        LDA(0, 0); LDB2(0);
        STAGE_B(1, 0, t1);
        BAR(); LGKM0();
        MFMA_Q(0, 0);
        BAR();

        // ph2: buf0 (mh0,nh1), pure MFMA (frags resident); stage A0(s2)->buf0
        STAGE_A(0, 0, s2);
        BAR(); LGKM0();
        MFMA_Q(0, 1);
        BAR();

        // ph3: buf0 (mh1,nh1); read A1; stage B1(s2)->buf0
        LDA(0, 1);
        STAGE_B(0, 1, s2);
        BAR(); LGKM0();
        MFMA_Q(1, 1);
        BAR();

        // ph4: buf0 (mh1,nh0), pure MFMA; stage A1(s2)->buf0; counted vmcnt
        STAGE_A(0, 1, s2);
        BAR(); LGKM0();
        MFMA_Q(1, 0);
        VM(6);
        BAR();

        // ph5: buf1 (mh0,nh0); read A0 + BOTH B halves; stage B0(s2)->buf0
        LDA(1, 0); LDB2(1);
        STAGE_B(0, 0, s2);
        BAR(); LGKM0();
        MFMA_Q(0, 0);
        BAR();

        // ph6: buf1 (mh0,nh1), pure MFMA; stage A0(s3)->buf1
        STAGE_A(1, 0, s3);
        BAR(); LGKM0();
        MFMA_Q(0, 1);
        BAR();

        // ph7: buf1 (mh1,nh1); read A1; stage B1(s3)->buf1
        LDA(1, 1);
        STAGE_B(1, 1, s3);
        BAR(); LGKM0();
        MFMA_Q(1, 1);
        BAR();

        // ph8: buf1 (mh1,nh0), pure MFMA; stage A1(s3)->buf1; counted vmcnt
        STAGE_A(1, 1, s3);
        BAR(); LGKM0();
        MFMA_Q(1, 0);
        VM(6);
        BAR();
    }

    VM(0);   // drain outstanding prefetches before epilogue

    // epilogue: C row = bm0+wm*128+i*16+lq*4+r, col = bn0+wn*64+j*16+lm
    const int cm0 = bm0 + wm * 128 + lq * 4;
    const int cn0 = bn0 + wn * 64 + lm;
#pragma unroll
    for (int nt2 = 0; nt2 < 4; ++nt2) {
        const int n = cn0 + nt2 * 16;
        const float bv = bias[n];
#pragma unroll
        for (int mt = 0; mt < 8; ++mt) {
            float* out = C + (size_t)(cm0 + mt * 16) * OUT_F + n;
#pragma unroll
            for (int r = 0; r < 4; ++r)
                out[(size_t)r * OUT_F] = acc[mt][nt2][r] + bv;
        }
    }

#undef STAGE_A
#undef STAGE_B
#undef LDA
#undef LDB2
#undef MFMA_Q
#undef BAR
#undef LGKM0
#undef VM
}

extern "C" void kernel_launch(void* const* d_in, const int* in_sizes, int n_in,
                              void* d_out, int out_size, void* d_ws, size_t ws_size,
                              hipStream_t stream) {
    const float* x       = (const float*)d_in[0];  // [4,2048,4096]
    const float* scales  = (const float*)d_in[1];  // [32,11008]
    const float* bias    = (const float*)d_in[2];  // [11008]
    const int*   qweight = (const int*)d_in[3];    // [512,11008]
    const int*   qzeros  = (const int*)d_in[4];    // [32,1376]
    float* out = (float*)d_out;                    // [8192,11008]

    // workspace: xb (67,108,864 B) | wt (90,177,536 B)
    ushort* xb = (ushort*)d_ws;
    ushort* wt = (ushort*)((char*)d_ws + (size_t)M_TOT * IN_F * 2);

    convert_x<<<(M_TOT * IN_F / 8) / 256, 256, 0, stream>>>((const float4*)x, (ushort8*)xb);
    dequant_w<<<(OUT_F / 64) * (KK_ROWS / 64), 256, 0, stream>>>(qweight, qzeros, scales, wt);
    gemm_bf16<<<NWG, 512, 0, stream>>>(xb, wt, bias, out);
}